// Round 11
// baseline (329.572 us; speedup 1.0000x reference)
//
#include <hip/hip_runtime.h>
#include <hip/hip_bf16.h>

typedef unsigned int u32;
typedef unsigned short u16;

__device__ __forceinline__ u16 f2bf(float f){ u32 x; __builtin_memcpy(&x,&f,4); u32 r=(x+0x7fffu+((x>>16)&1u))>>16; return (u16)r; }
__device__ __forceinline__ float lo2f(u32 u){ u32 x=u<<16; float f; __builtin_memcpy(&f,&x,4); return f; }
__device__ __forceinline__ float hi2f(u32 u){ u32 x=u&0xffff0000u; float f; __builtin_memcpy(&f,&x,4); return f; }

// ---------------- K0: transpose x (32 x 4096) -> xt (4096 x 32) ----------------
__global__ __launch_bounds__(256) void transpose_x(
    const float* __restrict__ x, float* __restrict__ xt)
{
    __shared__ float ld[32][65];
    const int t = threadIdx.x;
    const int g = blockIdx.x;
    #pragma unroll
    for (int i=0;i<8;++i) {
        const int e = i*256 + t;
        const int b = e >> 6, dd = e & 63;
        ld[b][dd] = x[(size_t)b*4096 + g*64 + dd];
    }
    __syncthreads();
    #pragma unroll
    for (int i=0;i<8;++i) {
        const int e = i*256 + t;
        const int dd = e >> 5, b = e & 31;
        xt[(size_t)(g*64 + dd)*32 + b] = ld[b][dd];
    }
}

// ---------------- K1/K3: split-K GEMM with transposed A: (K x 32) ----------------
__global__ __launch_bounds__(256) void gemm_splitk_t(
    const float* __restrict__ At, const float2* __restrict__ W2,
    float* __restrict__ P, int K, int N, int dps)
{
    const int j2 = blockIdx.x*256 + threadIdx.x;
    const int s = blockIdx.y;
    float acc0[32], acc1[32];
    #pragma unroll
    for (int b=0;b<32;++b){ acc0[b]=0.f; acc1[b]=0.f; }
    const int d0 = s*dps, d1 = d0 + dps;
    const int halfN = N >> 1;
    #pragma unroll 2
    for (int d=d0; d<d1; ++d) {
        const float2 wv = W2[(size_t)d*halfN + j2];
        const float* __restrict__ Ad = At + d*32;   // contiguous 128B, wave-uniform -> s_load
        #pragma unroll
        for (int b=0;b<32;++b) {
            const float av = Ad[b];
            acc0[b] = fmaf(av, wv.x, acc0[b]);
            acc1[b] = fmaf(av, wv.y, acc1[b]);
        }
    }
    float* Pp = P + (size_t)(s*32)*N + 2*j2;
    #pragma unroll
    for (int b=0;b<32;++b)
        *reinterpret_cast<float2*>(Pp + (size_t)b*N) = make_float2(acc0[b], acc1[b]);
}

// ---------------- K2: reduce partials + RoPE + pack q/k/v (partner via LDS) ----------------
__global__ __launch_bounds__(256) void qkv_finish(
    const float* __restrict__ P, const float* __restrict__ cosc,
    const float* __restrict__ sinc, const int* __restrict__ spp,
    float* __restrict__ qws, float* __restrict__ kn, float* __restrict__ vn,
    int splits)
{
    __shared__ float sh[256];
    const int t = threadIdx.x;
    const int col = blockIdx.x*256 + t;
    const int b = blockIdx.y;
    float v = 0.f;
    for (int s=0;s<splits;++s) v += P[(size_t)(s*32+b)*6144 + col];
    sh[t] = v;
    __syncthreads();
    if (col < 5120) {
        const int d = col & 127;
        const int pt = (t & ~127) | ((d<64)? d+64 : d-64);
        const float pv = sh[pt];
        const int spos = *spp;
        const float c  = cosc[spos*128 + d];
        const float sn = sinc[spos*128 + d];
        const float rot = (d<64)? -pv : pv;
        const float val = fmaf(v, c, rot*sn);
        if (col < 4096) qws[(size_t)b*4096 + col] = val;
        else            kn[(size_t)b*1024 + (col-4096)] = val;
    } else {
        vn[(size_t)b*1024 + (col-5120)] = v;
    }
}

// ---------------- K4a: flash-split attention part. grid 2048 = (mat, part), block 256 = 4 waves ----------------
__global__ __launch_bounds__(256, 4) void attn_part(
    const float* __restrict__ qws, const float* __restrict__ Kc,
    const float* __restrict__ Vc, const float* __restrict__ kn,
    const float* __restrict__ vn, const float* __restrict__ mask,
    const int* __restrict__ curp, float* __restrict__ partO,
    float* __restrict__ partML, const int PL, const int SW)
{
    __shared__ float scoresS[4*512];      // scores [h][512]; reused in-place for packed bf16 probs
    __shared__ float obuf[4][4][128];
    __shared__ float redm[4][4];
    __shared__ float reds[4][4];

    const int t = threadIdx.x;
    const int lane = t & 63;
    const int w = t >> 6;
    const int mat  = blockIdx.x >> 3;
    const int part = blockIdx.x & 7;
    const int b  = mat >> 3;
    const int kv = mat & 7;
    const int cur = *curp;
    const int PS = PL >> 3;               // positions per part (504)
    const int base = part * PS;

    const float* __restrict__ Kb  = Kc + (size_t)mat*SW*128;
    const float* __restrict__ knr = kn + (size_t)mat*128;
    const float* __restrict__ qbase = qws + (size_t)(b*32 + kv*4)*128;

    // ---- Phase A: cooperative QK^T. 16-lane group per row; lane l covers d=[8l,8l+8). ----
    const int l   = lane & 15;
    const int grp = lane >> 4;
    float qv[4][8];
    #pragma unroll
    for (int h=0;h<4;++h)
        #pragma unroll
        for (int j=0;j<8;++j)
            qv[h][j] = qbase[h*128 + l*8 + j];

    const int nIter = (PS + 15) >> 4;
    for (int i=0;i<nIter;++i) {
        const int rl = i*16 + w*4 + grp;   // local row
        if (rl < PS) {
            const int r = base + rl;
            const float* __restrict__ row = (r==cur) ? knr : (Kb + (size_t)r*128);
            const float4 ka  = *reinterpret_cast<const float4*>(row + l*8);
            const float4 kb4 = *reinterpret_cast<const float4*>(row + l*8 + 4);
            float kf[8];
            kf[0]=ka.x; kf[1]=ka.y; kf[2]=ka.z; kf[3]=ka.w;
            kf[4]=kb4.x; kf[5]=kb4.y; kf[6]=kb4.z; kf[7]=kb4.w;
            float sc0=0.f, sc1=0.f, sc2=0.f, sc3=0.f;
            #pragma unroll
            for (int j=0;j<8;++j) {
                sc0 = fmaf(qv[0][j], kf[j], sc0);
                sc1 = fmaf(qv[1][j], kf[j], sc1);
                sc2 = fmaf(qv[2][j], kf[j], sc2);
                sc3 = fmaf(qv[3][j], kf[j], sc3);
            }
            #pragma unroll
            for (int off=8; off; off>>=1) {
                sc0 += __shfl_xor(sc0, off, 16);
                sc1 += __shfl_xor(sc1, off, 16);
                sc2 += __shfl_xor(sc2, off, 16);
                sc3 += __shfl_xor(sc3, off, 16);
            }
            if (l < 4) {
                const float v = (l==0)?sc0:(l==1)?sc1:(l==2)?sc2:sc3;
                scoresS[l*512 + rl] = v;
            }
        }
    }
    __syncthreads();

    // ---- Phase B: scale + mask + LOCAL softmax ----
    const float scale = 0.08838834764831845f; // 1/sqrt(128)
    const size_t mbase = ((size_t)b*32 + (size_t)kv*4)*(size_t)PL;
    float s[4][2];
    #pragma unroll
    for (int i=0;i<2;++i) {
        const int p = i*256 + t;
        if (p < PS) {
            const int gp = base + p;
            #pragma unroll
            for (int h=0;h<4;++h) {
                const float mv = mask[mbase + (size_t)h*PL + gp];
                s[h][i] = fmaf(scoresS[h*512 + p], scale, mv);
            }
        } else {
            #pragma unroll
            for (int h=0;h<4;++h) s[h][i] = -3.0e38f;
        }
    }

    float lm[4];
    #pragma unroll
    for (int h=0;h<4;++h) lm[h] = fmaxf(s[h][0], s[h][1]);
    #pragma unroll
    for (int off=1; off<64; off<<=1) {
        #pragma unroll
        for (int h=0;h<4;++h) lm[h] = fmaxf(lm[h], __shfl_xor(lm[h], off, 64));
    }
    if (lane==0) {
        #pragma unroll
        for (int h=0;h<4;++h) redm[w][h] = lm[h];
    }
    __syncthreads();
    float M[4];
    #pragma unroll
    for (int h=0;h<4;++h)
        M[h] = fmaxf(fmaxf(redm[0][h],redm[1][h]), fmaxf(redm[2][h],redm[3][h]));

    float ls[4] = {0.f,0.f,0.f,0.f};
    #pragma unroll
    for (int i=0;i<2;++i) {
        #pragma unroll
        for (int h=0;h<4;++h) {
            const float e = __expf(s[h][i] - M[h]);
            s[h][i] = e;
            ls[h] += e;
        }
    }
    #pragma unroll
    for (int off=1; off<64; off<<=1) {
        #pragma unroll
        for (int h=0;h<4;++h) ls[h] += __shfl_xor(ls[h], off, 64);
    }
    if (lane==0) {
        #pragma unroll
        for (int h=0;h<4;++h) reds[w][h] = ls[h];
    }
    __syncthreads();
    float lsum[4];
    #pragma unroll
    for (int h=0;h<4;++h)
        lsum[h] = reds[0][h]+reds[1][h]+reds[2][h]+reds[3][h];

    // ---- write UNNORMALIZED probs e^(s-m) bf16-packed, in place over scoresS ----
    #pragma unroll
    for (int i=0;i<2;++i) {
        const int p = i*256 + t;
        if (p < PS) {
            const u32 plo = (u32)f2bf(s[0][i]) | ((u32)f2bf(s[1][i]) << 16);
            const u32 phi = (u32)f2bf(s[2][i]) | ((u32)f2bf(s[3][i]) << 16);
            *reinterpret_cast<u32*>(&scoresS[p])       = plo;
            *reinterpret_cast<u32*>(&scoresS[512 + p]) = phi;
        }
    }
    __syncthreads();

    // ---- Phase PV: wave w covers local rows [w*PS/4, ...); lane covers d=2*lane,2*lane+1 ----
    const float* __restrict__ Vb  = Vc + (size_t)mat*SW*128;
    const float* __restrict__ vnr = vn + (size_t)mat*128;
    const int chunk = PS >> 2;
    const int p0 = w*chunk, p1 = p0 + chunk;
    float a0[4] = {0.f,0.f,0.f,0.f}, a1[4] = {0.f,0.f,0.f,0.f};
    #pragma unroll 4
    for (int p=p0; p<p1; ++p) {
        const int gr = base + p;
        const float* row = (gr==cur) ? vnr : (Vb + (size_t)gr*128);
        const float2 vv = *reinterpret_cast<const float2*>(row + 2*lane);
        const u32 ppl = *reinterpret_cast<const u32*>(&scoresS[p]);
        const u32 pph = *reinterpret_cast<const u32*>(&scoresS[512 + p]);
        const float pr0 = lo2f(ppl), pr1 = hi2f(ppl);
        const float pr2 = lo2f(pph), pr3 = hi2f(pph);
        a0[0]=fmaf(pr0,vv.x,a0[0]); a1[0]=fmaf(pr0,vv.y,a1[0]);
        a0[1]=fmaf(pr1,vv.x,a0[1]); a1[1]=fmaf(pr1,vv.y,a1[1]);
        a0[2]=fmaf(pr2,vv.x,a0[2]); a1[2]=fmaf(pr2,vv.y,a1[2]);
        a0[3]=fmaf(pr3,vv.x,a0[3]); a1[3]=fmaf(pr3,vv.y,a1[3]);
    }
    #pragma unroll
    for (int h=0;h<4;++h)
        *reinterpret_cast<float2*>(&obuf[w][h][2*lane]) = make_float2(a0[h], a1[h]);
    __syncthreads();

    // ---- cross-wave reduce + partial writeout ----
    #pragma unroll
    for (int rr=0; rr<2; ++rr) {
        const int idx = rr*256 + t;
        const int h = idx >> 7;
        const int d = idx & 127;
        const float sum = obuf[0][h][d]+obuf[1][h][d]+obuf[2][h][d]+obuf[3][h][d];
        partO[(size_t)blockIdx.x*512 + idx] = sum;
    }
    if (t < 4) {
        partML[(size_t)blockIdx.x*8 + t]     = M[t];
        partML[(size_t)blockIdx.x*8 + 4 + t] = lsum[t];
    }
}

// ---------------- K4b: combine 8 flash parts ----------------
__global__ __launch_bounds__(512) void attn_combine(
    const float* __restrict__ partO, const float* __restrict__ partML,
    float* __restrict__ aout_t)
{
    const int mat = blockIdx.x;
    const int t = threadIdx.x;
    const int h = t >> 7, d = t & 127;
    float m_[8], l_[8];
    float M = -3.0e38f;
    #pragma unroll
    for (int p=0;p<8;++p) {
        m_[p] = partML[(size_t)(mat*8+p)*8 + h];
        l_[p] = partML[(size_t)(mat*8+p)*8 + 4 + h];
        M = fmaxf(M, m_[p]);
    }
    float num = 0.f, den = 0.f;
    #pragma unroll
    for (int p=0;p<8;++p) {
        const float sc = __expf(m_[p] - M);
        num = fmaf(sc, partO[(size_t)(mat*8+p)*512 + t], num);
        den = fmaf(sc, l_[p], den);
    }
    const int b = mat >> 3, kv = mat & 7;
    const int col = (kv*4 + h)*128 + d;
    aout_t[(size_t)col*32 + b] = num/den;
}

// ---------------- K5: reduce wo partials -> f32 output ----------------
__global__ __launch_bounds__(256) void wo_finish(
    const float* __restrict__ P, float* __restrict__ out, int splits)
{
    const int col = blockIdx.x*256 + threadIdx.x;
    const int b = blockIdx.y;
    float v = 0.f;
    for (int s=0;s<splits;++s) v += P[(size_t)(s*32+b)*4096 + col];
    out[(size_t)b*4096 + col] = v;
}

extern "C" void kernel_launch(void* const* d_in, const int* in_sizes, int n_in,
                              void* d_out, int out_size, void* d_ws, size_t ws_size,
                              hipStream_t stream)
{
    const float* x    = (const float*)d_in[0];
    const float* wqkv = (const float*)d_in[1];
    const float* wo   = (const float*)d_in[2];
    const float* cK   = (const float*)d_in[3];
    const float* cV   = (const float*)d_in[4];
    const float* cosc = (const float*)d_in[5];
    const float* sinc = (const float*)d_in[6];
    const float* mask = (const float*)d_in[7];
    const int* sp   = (const int*)d_in[8];
    const int* cp   = (const int*)d_in[9];

    const int PL = in_sizes[7] / (32*32);          // padded_len (4032)
    const int SW = in_sizes[3] / (32*8*128);       // cache rows (4096)

    char* ws = (char*)d_ws;
    float* xt    = (float*)(ws);                         // 512 KB
    float* qws   = (float*)(ws + 524288);                // 512 KB
    float* aout_t= (float*)(ws + 2*524288);              // 512 KB
    float* kn    = (float*)(ws + 3*524288);              // 128 KB
    float* vn    = (float*)(ws + 3*524288 + 131072);     // 128 KB
    float* Pbuf  = (float*)(ws + 3*524288 + 2*131072);   // split-K partials (<= 50.4 MB)
    float* partO = (float*)(ws + 3*524288 + 2*131072 + 50331648);   // 4 MB
    float* partML= (float*)(ws + 3*524288 + 2*131072 + 50331648 + 4194304); // 64 KB

    int splits = 64;
    {
        while (splits > 4 && (size_t)splits*32*6144*4 > 50331648ull) splits >>= 1;
    }
    const int dps = 4096 / splits;

    transpose_x<<<64, 256, 0, stream>>>(x, xt);
    gemm_splitk_t<<<dim3(12, splits), 256, 0, stream>>>(xt, (const float2*)wqkv, Pbuf, 4096, 6144, dps);
    qkv_finish<<<dim3(24, 32), 256, 0, stream>>>(Pbuf, cosc, sinc, sp, qws, kn, vn, splits);

    attn_part<<<2048, 256, 0, stream>>>(qws, cK, cV, kn, vn, mask, cp, partO, partML, PL, SW);
    attn_combine<<<256, 512, 0, stream>>>(partO, partML, aout_t);

    gemm_splitk_t<<<dim3(8, splits), 256, 0, stream>>>(aout_t, (const float2*)wo, Pbuf, 4096, 4096, dps);
    wo_finish<<<dim3(16, 32), 256, 0, stream>>>(Pbuf, (float*)d_out, splits);
}

// Round 12
// 310.655 us; speedup vs baseline: 1.0609x; 1.0609x over previous
//
#include <hip/hip_runtime.h>
#include <hip/hip_bf16.h>

typedef unsigned int u32;
typedef unsigned short u16;

__device__ __forceinline__ u16 f2bf(float f){ u32 x; __builtin_memcpy(&x,&f,4); u32 r=(x+0x7fffu+((x>>16)&1u))>>16; return (u16)r; }
__device__ __forceinline__ float lo2f(u32 u){ u32 x=u<<16; float f; __builtin_memcpy(&f,&x,4); return f; }
__device__ __forceinline__ float hi2f(u32 u){ u32 x=u&0xffff0000u; float f; __builtin_memcpy(&f,&x,4); return f; }

// ---------------- K0: transpose x (32 x 4096) -> xt (4096 x 32) ----------------
__global__ __launch_bounds__(256) void transpose_x(
    const float* __restrict__ x, float* __restrict__ xt)
{
    __shared__ float ld[32][65];
    const int t = threadIdx.x;
    const int g = blockIdx.x;
    #pragma unroll
    for (int i=0;i<8;++i) {
        const int e = i*256 + t;
        const int b = e >> 6, dd = e & 63;
        ld[b][dd] = x[(size_t)b*4096 + g*64 + dd];
    }
    __syncthreads();
    #pragma unroll
    for (int i=0;i<8;++i) {
        const int e = i*256 + t;
        const int dd = e >> 5, b = e & 31;
        xt[(size_t)(g*64 + dd)*32 + b] = ld[b][dd];
    }
}

// ---------------- K1/K3: split-K GEMM with transposed A: (K x 32) ----------------
__global__ __launch_bounds__(256) void gemm_splitk_t(
    const float* __restrict__ At, const float2* __restrict__ W2,
    float* __restrict__ P, int K, int N, int dps)
{
    const int j2 = blockIdx.x*256 + threadIdx.x;
    const int s = blockIdx.y;
    float acc0[32], acc1[32];
    #pragma unroll
    for (int b=0;b<32;++b){ acc0[b]=0.f; acc1[b]=0.f; }
    const int d0 = s*dps, d1 = d0 + dps;
    const int halfN = N >> 1;
    #pragma unroll 2
    for (int d=d0; d<d1; ++d) {
        const float2 wv = W2[(size_t)d*halfN + j2];
        const float* __restrict__ Ad = At + d*32;   // contiguous 128B, wave-uniform -> s_load
        #pragma unroll
        for (int b=0;b<32;++b) {
            const float av = Ad[b];
            acc0[b] = fmaf(av, wv.x, acc0[b]);
            acc1[b] = fmaf(av, wv.y, acc1[b]);
        }
    }
    float* Pp = P + (size_t)(s*32)*N + 2*j2;
    #pragma unroll
    for (int b=0;b<32;++b)
        *reinterpret_cast<float2*>(Pp + (size_t)b*N) = make_float2(acc0[b], acc1[b]);
}

// ---------------- K2: reduce partials + RoPE + pack q/k/v (partner via LDS) ----------------
__global__ __launch_bounds__(256) void qkv_finish(
    const float* __restrict__ P, const float* __restrict__ cosc,
    const float* __restrict__ sinc, const int* __restrict__ spp,
    float* __restrict__ qws, float* __restrict__ kn, float* __restrict__ vn,
    int splits)
{
    __shared__ float sh[256];
    const int t = threadIdx.x;
    const int col = blockIdx.x*256 + t;
    const int b = blockIdx.y;
    float v = 0.f;
    for (int s=0;s<splits;++s) v += P[(size_t)(s*32+b)*6144 + col];
    sh[t] = v;
    __syncthreads();
    if (col < 5120) {
        const int d = col & 127;
        const int pt = (t & ~127) | ((d<64)? d+64 : d-64);
        const float pv = sh[pt];
        const int spos = *spp;
        const float c  = cosc[spos*128 + d];
        const float sn = sinc[spos*128 + d];
        const float rot = (d<64)? -pv : pv;
        const float val = fmaf(v, c, rot*sn);
        if (col < 4096) qws[(size_t)b*4096 + col] = val;
        else            kn[(size_t)b*1024 + (col-4096)] = val;
    } else {
        vn[(size_t)b*1024 + (col-5120)] = v;
    }
}

// ---------------- K4: fused attention, 16 waves/block; coalesced QK^T (R9 version) ----------------
__global__ __launch_bounds__(1024, 4) void attn_kernel(
    const float* __restrict__ qws, const float* __restrict__ Kc,
    const float* __restrict__ Vc, const float* __restrict__ kn,
    const float* __restrict__ vn, const float* __restrict__ mask,
    const int* __restrict__ curp, float* __restrict__ aout_t,
    const int PL, const int SW)
{
    __shared__ float scoresS[4*4100];     // 64.1 KB raw scores [h][p]
    __shared__ uint2 probsP[4096];        // 32 KB: 4 bf16 probs per position
    __shared__ float obuf[16][4][128];    // 32 KB
    __shared__ float redm[16][4];
    __shared__ float reds[16][4];

    const int t = threadIdx.x;
    const int lane = t & 63;
    const int w = t >> 6;
    const int b  = blockIdx.x >> 3;
    const int kv = blockIdx.x & 7;
    const int cur = *curp;

    const size_t mat = (size_t)(b*8+kv);
    const float* __restrict__ Kb  = Kc + mat*(size_t)SW*128;
    const float* __restrict__ knr = kn + mat*128;
    const float* __restrict__ qbase = qws + (size_t)(b*32 + kv*4)*128;

    // ---- Phase A: cooperative QK^T. 16-lane group per row; lane l covers d=[8l,8l+8). ----
    const int l   = lane & 15;
    const int grp = lane >> 4;
    float qv[4][8];
    #pragma unroll
    for (int h=0;h<4;++h)
        #pragma unroll
        for (int j=0;j<8;++j)
            qv[h][j] = qbase[h*128 + l*8 + j];

    const int rpw = PL >> 4;           // rows per wave (252); PL % 64 == 0
    const int rb0 = w * rpw;
    for (int g=0; g<rpw; g+=4) {
        const int r = rb0 + g + grp;
        const float* __restrict__ row = (r==cur) ? knr : (Kb + (size_t)r*128);
        const float4 ka = *reinterpret_cast<const float4*>(row + l*8);
        const float4 kb4 = *reinterpret_cast<const float4*>(row + l*8 + 4);
        float kf[8];
        kf[0]=ka.x; kf[1]=ka.y; kf[2]=ka.z; kf[3]=ka.w;
        kf[4]=kb4.x; kf[5]=kb4.y; kf[6]=kb4.z; kf[7]=kb4.w;
        float sc0=0.f, sc1=0.f, sc2=0.f, sc3=0.f;
        #pragma unroll
        for (int j=0;j<8;++j) {
            sc0 = fmaf(qv[0][j], kf[j], sc0);
            sc1 = fmaf(qv[1][j], kf[j], sc1);
            sc2 = fmaf(qv[2][j], kf[j], sc2);
            sc3 = fmaf(qv[3][j], kf[j], sc3);
        }
        #pragma unroll
        for (int off=8; off; off>>=1) {
            sc0 += __shfl_xor(sc0, off, 16);
            sc1 += __shfl_xor(sc1, off, 16);
            sc2 += __shfl_xor(sc2, off, 16);
            sc3 += __shfl_xor(sc3, off, 16);
        }
        if (l < 4) {
            const float v = (l==0)?sc0:(l==1)?sc1:(l==2)?sc2:sc3;
            scoresS[l*4100 + r] = v;
        }
    }
    __syncthreads();

    // ---- Phase B: scale + mask + softmax ----
    const float scale = 0.08838834764831845f; // 1/sqrt(128)
    const size_t mbase = ((size_t)b*32 + (size_t)kv*4)*(size_t)PL;
    float s[4][4];
    #pragma unroll
    for (int i=0;i<4;++i) {
        const int p = i*1024 + t;
        if (p < PL) {
            #pragma unroll
            for (int h=0;h<4;++h) {
                const float mv = mask[mbase + (size_t)h*PL + p];
                s[h][i] = fmaf(scoresS[h*4100 + p], scale, mv);
            }
        } else {
            #pragma unroll
            for (int h=0;h<4;++h) s[h][i] = -3.0e38f;
        }
    }

    float lm[4];
    #pragma unroll
    for (int h=0;h<4;++h)
        lm[h] = fmaxf(fmaxf(s[h][0],s[h][1]), fmaxf(s[h][2],s[h][3]));
    #pragma unroll
    for (int off=1; off<64; off<<=1) {
        #pragma unroll
        for (int h=0;h<4;++h) lm[h] = fmaxf(lm[h], __shfl_xor(lm[h], off, 64));
    }
    if (lane==0) {
        #pragma unroll
        for (int h=0;h<4;++h) redm[w][h] = lm[h];
    }
    __syncthreads();
    float M[4];
    #pragma unroll
    for (int h=0;h<4;++h) {
        float m = redm[0][h];
        #pragma unroll
        for (int ww=1;ww<16;++ww) m = fmaxf(m, redm[ww][h]);
        M[h] = m;
    }

    float ls[4] = {0.f,0.f,0.f,0.f};
    #pragma unroll
    for (int i=0;i<4;++i) {
        #pragma unroll
        for (int h=0;h<4;++h) {
            const float e = __expf(s[h][i] - M[h]);
            s[h][i] = e;
            ls[h] += e;
        }
    }
    #pragma unroll
    for (int off=1; off<64; off<<=1) {
        #pragma unroll
        for (int h=0;h<4;++h) ls[h] += __shfl_xor(ls[h], off, 64);
    }
    if (lane==0) {
        #pragma unroll
        for (int h=0;h<4;++h) reds[w][h] = ls[h];
    }
    __syncthreads();
    float inv[4];
    #pragma unroll
    for (int h=0;h<4;++h) {
        float sm = reds[0][h];
        #pragma unroll
        for (int ww=1;ww<16;++ww) sm += reds[ww][h];
        inv[h] = 1.f / sm;
    }

    #pragma unroll
    for (int i=0;i<4;++i) {
        const int p = i*1024 + t;
        if (p < PL) {
            const u32 plo = (u32)f2bf(s[0][i]*inv[0]) | ((u32)f2bf(s[1][i]*inv[1]) << 16);
            const u32 phi = (u32)f2bf(s[2][i]*inv[2]) | ((u32)f2bf(s[3][i]*inv[3]) << 16);
            probsP[p] = make_uint2(plo, phi);
        }
    }
    __syncthreads();

    // ---- Phase PV: wave w covers its row chunk; lane covers d=2*lane,2*lane+1 (coalesced) ----
    const float* __restrict__ Vb  = Vc + mat*(size_t)SW*128;
    const float* __restrict__ vnr = vn + mat*128;
    const int chunk = PL >> 4;
    const int p0 = w*chunk, p1 = p0 + chunk;
    float a0[4] = {0.f,0.f,0.f,0.f}, a1[4] = {0.f,0.f,0.f,0.f};
    #pragma unroll 8
    for (int p=p0; p<p1; ++p) {
        const float* row = (p==cur) ? vnr : (Vb + (size_t)p*128);
        const float2 vv = *reinterpret_cast<const float2*>(row + 2*lane);
        const uint2 pp = probsP[p];
        const float pr0 = lo2f(pp.x), pr1 = hi2f(pp.x);
        const float pr2 = lo2f(pp.y), pr3 = hi2f(pp.y);
        a0[0]=fmaf(pr0,vv.x,a0[0]); a1[0]=fmaf(pr0,vv.y,a1[0]);
        a0[1]=fmaf(pr1,vv.x,a0[1]); a1[1]=fmaf(pr1,vv.y,a1[1]);
        a0[2]=fmaf(pr2,vv.x,a0[2]); a1[2]=fmaf(pr2,vv.y,a1[2]);
        a0[3]=fmaf(pr3,vv.x,a0[3]); a1[3]=fmaf(pr3,vv.y,a1[3]);
    }
    #pragma unroll
    for (int h=0;h<4;++h)
        *reinterpret_cast<float2*>(&obuf[w][h][2*lane]) = make_float2(a0[h], a1[h]);
    __syncthreads();

    // ---- cross-wave reduce + TRANSPOSED writeout (for wo GEMM) ----
    if (t < 512) {
        const int h = t >> 7;
        const int d = t & 127;
        float sum = obuf[0][h][d];
        #pragma unroll
        for (int ww=1;ww<16;++ww) sum += obuf[ww][h][d];
        const int col = (kv*4 + h)*128 + d;
        aout_t[(size_t)col*32 + b] = sum;
    }
}

// ---------------- K5: reduce wo partials -> f32 output ----------------
__global__ __launch_bounds__(256) void wo_finish(
    const float* __restrict__ P, float* __restrict__ out, int splits)
{
    const int col = blockIdx.x*256 + threadIdx.x;
    const int b = blockIdx.y;
    float v = 0.f;
    for (int s=0;s<splits;++s) v += P[(size_t)(s*32+b)*4096 + col];
    out[(size_t)b*4096 + col] = v;
}

extern "C" void kernel_launch(void* const* d_in, const int* in_sizes, int n_in,
                              void* d_out, int out_size, void* d_ws, size_t ws_size,
                              hipStream_t stream)
{
    const float* x    = (const float*)d_in[0];
    const float* wqkv = (const float*)d_in[1];
    const float* wo   = (const float*)d_in[2];
    const float* cK   = (const float*)d_in[3];
    const float* cV   = (const float*)d_in[4];
    const float* cosc = (const float*)d_in[5];
    const float* sinc = (const float*)d_in[6];
    const float* mask = (const float*)d_in[7];
    const int* sp   = (const int*)d_in[8];
    const int* cp   = (const int*)d_in[9];

    const int PL = in_sizes[7] / (32*32);          // padded_len (4032)
    const int SW = in_sizes[3] / (32*8*128);       // cache rows (4096)

    char* ws = (char*)d_ws;
    float* xt    = (float*)(ws);                         // 512 KB
    float* qws   = (float*)(ws + 524288);                // 512 KB
    float* aout_t= (float*)(ws + 2*524288);              // 512 KB
    float* kn    = (float*)(ws + 3*524288);              // 128 KB
    float* vn    = (float*)(ws + 3*524288 + 131072);     // 128 KB
    float* Pbuf  = (float*)(ws + 3*524288 + 2*131072);   // split-K partials (25.2 MB @ splits=32)

    const int splits = 32;
    const int dps = 4096 / splits;                       // 128

    transpose_x<<<64, 256, 0, stream>>>(x, xt);
    gemm_splitk_t<<<dim3(12, splits), 256, 0, stream>>>(xt, (const float2*)wqkv, Pbuf, 4096, 6144, dps);
    qkv_finish<<<dim3(24, 32), 256, 0, stream>>>(Pbuf, cosc, sinc, sp, qws, kn, vn, splits);

    attn_kernel<<<256, 1024, 0, stream>>>(qws, cK, cV, kn, vn, mask, cp, aout_t, PL, SW);

    gemm_splitk_t<<<dim3(8, splits), 256, 0, stream>>>(aout_t, (const float2*)wo, Pbuf, 4096, 4096, dps);
    wo_finish<<<dim3(16, 32), 256, 0, stream>>>(Pbuf, (float*)d_out, splits);
}